// Round 2
// baseline (676.731 us; speedup 1.0000x reference)
//
#include <hip/hip_runtime.h>
#include <cstdint>
#include <cstddef>

#define NF 10240

typedef _Float16 half8_t __attribute__((ext_vector_type(8)));
typedef _Float16 half4_t __attribute__((ext_vector_type(4)));
typedef float floatx4 __attribute__((ext_vector_type(4)));

// ---------------------------------------------------------------------------
// k_prep: one streaming pass over supports (fp32).  Produces:
//   - Ah:  fp16 copy of A' (self-loop-fixed), row-major (210 MB)
//   - deg: column sums of A' (LDS-reduced; 32 atomics per address total)
// Tile: 320 i-rows x 128 j-cols per block.  Each wave reads one full row
// segment (64 lanes x 16 B = 1 KB contiguous) -> ideal coalescing.
// ---------------------------------------------------------------------------
__global__ __launch_bounds__(256) void k_prep(const float* __restrict__ sup,
                                              _Float16* __restrict__ Ah,
                                              float* __restrict__ deg) {
  __shared__ float lsum[8 * 128];
  const int t = threadIdx.x;
  const int j0 = blockIdx.x * 128;
  const int i0 = blockIdx.y * 320;
  const int cq = t & 31;   // column quad (4 floats)
  const int rg = t >> 5;   // row-in-pass 0..7
  const int j = j0 + cq * 4;
  float4 s4 = {0.f, 0.f, 0.f, 0.f};
  const bool diagBlock = (i0 < j0 + 128) && (j0 < i0 + 320);
#pragma unroll 4
  for (int p = 0; p < 40; ++p) {
    const int i = i0 + p * 8 + rg;
    float4 v = *(const float4*)(sup + (size_t)i * NF + j);
    if (diagBlock) {
      if (i == j     && v.x == 0.f) v.x = 1.f;
      if (i == j + 1 && v.y == 0.f) v.y = 1.f;
      if (i == j + 2 && v.z == 0.f) v.z = 1.f;
      if (i == j + 3 && v.w == 0.f) v.w = 1.f;
    }
    s4.x += v.x; s4.y += v.y; s4.z += v.z; s4.w += v.w;
    half4_t h;
    h[0] = (_Float16)v.x; h[1] = (_Float16)v.y;
    h[2] = (_Float16)v.z; h[3] = (_Float16)v.w;
    *(half4_t*)(Ah + (size_t)i * NF + j) = h;   // 8-B coalesced store
  }
  lsum[rg * 128 + cq * 4 + 0] = s4.x;
  lsum[rg * 128 + cq * 4 + 1] = s4.y;
  lsum[rg * 128 + cq * 4 + 2] = s4.z;
  lsum[rg * 128 + cq * 4 + 3] = s4.w;
  __syncthreads();
  if (t < 128) {
    float s = 0.f;
#pragma unroll
    for (int r = 0; r < 8; ++r) s += lsum[r * 128 + t];
    atomicAdd(&deg[j0 + t], s);
  }
}

// ---------------------------------------------------------------------------
// k_g: h[b,i,:] = xf[b,i,:] @ W_gcn, g = dinv[i]*h, packed fp16 into MFMA
// B-fragment layout: halfword index ((i>>3)*64 + (b*16+o))*8 + (i&7).
// ---------------------------------------------------------------------------
__global__ __launch_bounds__(256) void k_g(const float* __restrict__ x,
                                           const float* __restrict__ Wg,
                                           const float* __restrict__ deg,
                                           float* __restrict__ dinv,
                                           _Float16* __restrict__ gp) {
  __shared__ float w[256];
  w[threadIdx.x] = Wg[threadIdx.x];
  __syncthreads();
  const int t = blockIdx.x * 256 + threadIdx.x;   // b*NF + i
  const int b = t / NF;
  const int i = t % NF;
  float xv[16];
  const float* xp = x + (size_t)t * 16;
#pragma unroll
  for (int d = 0; d < 16; ++d) xv[d] = xp[d];
  const float dg = deg[i];
  const float di = dg > 0.f ? rsqrtf(dg) : 0.f;
  if (b == 0) dinv[i] = di;
  const int base = ((i >> 3) * 64 + b * 16) * 8 + (i & 7);
#pragma unroll
  for (int o = 0; o < 16; ++o) {
    float h = 0.f;
#pragma unroll
    for (int d = 0; d < 16; ++d) h += xv[d] * w[d * 16 + o];
    gp[base + o * 8] = (_Float16)(h * di);
  }
}

// ---------------------------------------------------------------------------
// k_gemm2: C_p[p][j][bo] = sum_{i in split p} Ah[i,j] * g[i,bo] via
// mfma_f32_16x16x32_f16.  Ah is fp16 row-major; staging packs (i,i+1) half
// pairs into u32 LDS words, layout [j][i] with 72-half row stride:
//   - staging b32 writes: <=8-way bank aliasing (cheap, hidden under HBM)
//   - fragment reads: 16-B aligned ds_read_b128, conflict-free (8-phase min)
// A-frag: lane(m=x,k=q*8+jj) = AhT[j=jbase+ms*16+x][i=k]; feeds MFMA with no
// per-element converts.  No diag fix here (done in k_prep).
// ---------------------------------------------------------------------------
__global__ __launch_bounds__(256) void k_gemm2(const _Float16* __restrict__ Ah,
                                               const half8_t* __restrict__ gp8,
                                               float* __restrict__ Cp,
                                               int kRange, int nchunk) {
  __shared__ unsigned int lds32[64 * 36];   // [j:64][i-pair:36 (32+pad)]
  const int tid = threadIdx.x;
  const int lane = tid & 63;
  const int w = tid >> 6;        // wave id = bo-slice
  const int x = lane & 15;
  const int q = lane >> 4;
  const int jbase = blockIdx.x * 64;
  const int kbase0 = blockIdx.y * kRange;
  const int cq = tid & 15;       // staging j-quad
  const int ip = tid >> 4;       // staging i-pair 0..15

  floatx4 acc[4] = {};

  for (int ch = 0; ch < nchunk; ++ch) {
    const int kbase = kbase0 + ch * 64;
    __syncthreads();                         // protect LDS from prev readers
#pragma unroll
    for (int p = 0; p < 2; ++p) {
      const int il = p * 32 + ip * 2;
      const _Float16* r0 = Ah + (size_t)(kbase + il) * NF + jbase + cq * 4;
      const ushort4 a0 = *(const ushort4*)r0;        // row i   (4 halves)
      const ushort4 a1 = *(const ushort4*)(r0 + NF); // row i+1 (4 halves)
      unsigned int* d = &lds32[(cq * 4) * 36 + p * 16 + ip];
      d[0]   = (unsigned)a0.x | ((unsigned)a1.x << 16);
      d[36]  = (unsigned)a0.y | ((unsigned)a1.y << 16);
      d[72]  = (unsigned)a0.z | ((unsigned)a1.z << 16);
      d[108] = (unsigned)a0.w | ((unsigned)a1.w << 16);
    }
    __syncthreads();
    const int k8base = kbase >> 3;
#pragma unroll
    for (int s = 0; s < 2; ++s) {
      const half8_t bfrag = gp8[(k8base + s * 4 + q) * 64 + w * 16 + x];
#pragma unroll
      for (int ms = 0; ms < 4; ++ms) {
        const half8_t afrag = *(const half8_t*)((const _Float16*)lds32 +
                                (ms * 16 + x) * 72 + s * 32 + q * 8);
        acc[ms] = __builtin_amdgcn_mfma_f32_16x16x32_f16(afrag, bfrag,
                                                         acc[ms], 0, 0, 0);
      }
    }
  }

  const size_t pbase = (size_t)blockIdx.y * NF;
#pragma unroll
  for (int ms = 0; ms < 4; ++ms) {
#pragma unroll
    for (int r = 0; r < 4; ++r) {
      const int j = jbase + ms * 16 + q * 4 + r;
      Cp[(pbase + j) * 64 + w * 16 + x] = acc[ms][r];
    }
  }
}

// ---------------------------------------------------------------------------
// k_out: per n: sum K-split partials, relu(dinv[j]*C + b_gcn), then
// (160) @ W_out(160,16) + b_out.  One block per n.
// ---------------------------------------------------------------------------
__global__ __launch_bounds__(256) void k_out(const float* __restrict__ Cp,
                                             const float* __restrict__ dinv,
                                             const float* __restrict__ bgcn,
                                             const float* __restrict__ Wout,
                                             const float* __restrict__ bout,
                                             float* __restrict__ out, int S) {
  __shared__ float wl[2560];
  __shared__ float tmp[640];
  const int n = blockIdx.x;
  const int t = threadIdx.x;
  for (int idx = t; idx < 2560; idx += 256) wl[idx] = Wout[idx];
  if (t < 160) {
    const int f = t >> 4, o = t & 15;
    const int j = n * 10 + f;
    const float di = dinv[j];
    const float bg = bgcn[o];
    for (int b = 0; b < 4; ++b) {
      float s = 0.f;
      for (int p = 0; p < S; ++p)
        s += Cp[((size_t)(p * NF + j)) * 64 + b * 16 + o];
      const float v = di * s + bg;
      tmp[b * 160 + t] = v > 0.f ? v : 0.f;
    }
  }
  __syncthreads();
  if (t < 64) {
    const int b = t >> 4, oc = t & 15;
    float acc = bout[oc];
    for (int k = 0; k < 160; ++k) acc += tmp[b * 160 + k] * wl[k * 16 + oc];
    out[((size_t)(b * 1024 + n)) * 16 + oc] = acc;
  }
}

// ---------------------------------------------------------------------------
extern "C" void kernel_launch(void* const* d_in, const int* in_sizes, int n_in,
                              void* d_out, int out_size, void* d_ws,
                              size_t ws_size, hipStream_t stream) {
  const float* x   = (const float*)d_in[0];   // (4,1024,10,16)
  const float* sup = (const float*)d_in[3];   // (10240,10240)
  const float* Wg  = (const float*)d_in[6];   // (16,16)
  const float* bg  = (const float*)d_in[7];   // (16,)
  const float* Wo  = (const float*)d_in[8];   // (160,16)
  const float* bo  = (const float*)d_in[9];   // (16,)
  float* out = (float*)d_out;

  char* ws = (char*)d_ws;
  float*     deg  = (float*)ws;                           // 40 KB
  float*     dinv = (float*)(ws + 40960);                 // 40 KB
  _Float16*  gp   = (_Float16*)(ws + 81920);              // 1.31 MB
  _Float16*  Ah   = (_Float16*)(ws + 1392640);            // 210 MB fp16 A'
  float*     Cp   = (float*)(ws + 1392640 + 209715200);   // 21 MB partials

  const int S = 8;                 // K-split factor
  const int kRange = NF / S;       // 1280
  const int nchunk = kRange / 64;  // 20

  hipMemsetAsync(deg, 0, NF * sizeof(float), stream);
  k_prep<<<dim3(80, 32), 256, 0, stream>>>(sup, Ah, deg);
  k_g<<<160, 256, 0, stream>>>(x, Wg, deg, dinv, gp);
  k_gemm2<<<dim3(160, S), 256, 0, stream>>>(Ah, (const half8_t*)gp, Cp,
                                            kRange, nchunk);
  k_out<<<1024, 256, 0, stream>>>(Cp, dinv, bg, Wo, bo, out, S);
}

// Round 4
// 636.816 us; speedup vs baseline: 1.0627x; 1.0627x over previous
//
#include <hip/hip_runtime.h>
#include <cstdint>
#include <cstddef>

#define NF 10240

typedef _Float16 half8_t __attribute__((ext_vector_type(8)));
typedef _Float16 half4_t __attribute__((ext_vector_type(4)));
typedef float floatx4 __attribute__((ext_vector_type(4)));
typedef float fvec4 __attribute__((ext_vector_type(4)));

// ---------------------------------------------------------------------------
// k_prep: single streaming pass over supports (fp32, nontemporal: no L3
// allocation, preserving L3 for Ah).  Produces:
//   - Ah:   fp16 copy of A' (self-loop-fixed), row-major (210 MB, L3-resident)
//   - degP: per-i-block partial column sums [32][NF] (no atomics, no memset)
// Grid (40 j-tiles x 32 i-tiles); block reads 320 rows x 1 KB.
// ---------------------------------------------------------------------------
__global__ __launch_bounds__(256) void k_prep(const float* __restrict__ sup,
                                              _Float16* __restrict__ Ah,
                                              float* __restrict__ degP) {
  __shared__ float lsum[4 * 256];
  const int t = threadIdx.x;
  const int j0 = blockIdx.x * 256;
  const int i0 = blockIdx.y * 320;
  const int cj = t & 63;    // column quad (4 floats)
  const int rg = t >> 6;    // row-in-pass 0..3
  const int j = j0 + cj * 4;
  fvec4 s4 = {0.f, 0.f, 0.f, 0.f};
  const bool diagBlock = (i0 < j0 + 256) && (j0 < i0 + 320);
#pragma unroll 4
  for (int p = 0; p < 80; ++p) {
    const int i = i0 + p * 4 + rg;
    const fvec4* src = (const fvec4*)(sup + (size_t)i * NF + j);
    fvec4 v = __builtin_nontemporal_load(src);
    if (diagBlock) {
      if (i == j     && v.x == 0.f) v.x = 1.f;
      if (i == j + 1 && v.y == 0.f) v.y = 1.f;
      if (i == j + 2 && v.z == 0.f) v.z = 1.f;
      if (i == j + 3 && v.w == 0.f) v.w = 1.f;
    }
    s4 += v;
    half4_t h;
    h[0] = (_Float16)v.x; h[1] = (_Float16)v.y;
    h[2] = (_Float16)v.z; h[3] = (_Float16)v.w;
    *(half4_t*)(Ah + (size_t)i * NF + j) = h;   // 8-B coalesced, L3-allocating
  }
  lsum[rg * 256 + cj * 4 + 0] = s4.x;
  lsum[rg * 256 + cj * 4 + 1] = s4.y;
  lsum[rg * 256 + cj * 4 + 2] = s4.z;
  lsum[rg * 256 + cj * 4 + 3] = s4.w;
  __syncthreads();
  float s = lsum[t] + lsum[256 + t] + lsum[512 + t] + lsum[768 + t];
  degP[(size_t)blockIdx.y * NF + j0 + t] = s;
}

// ---------------------------------------------------------------------------
// k_g: deg[i] = sum of 32 partials; h[b,i,:] = xf[b,i,:] @ W_gcn;
// g = dinv[i]*h packed fp16 into MFMA B-fragment layout:
// halfword index ((i>>3)*64 + (b*16+o))*8 + (i&7).  Writes dinv for k_out.
// ---------------------------------------------------------------------------
__global__ __launch_bounds__(256) void k_g(const float* __restrict__ x,
                                           const float* __restrict__ Wg,
                                           const float* __restrict__ degP,
                                           float* __restrict__ dinv,
                                           _Float16* __restrict__ gp) {
  __shared__ float w[256];
  w[threadIdx.x] = Wg[threadIdx.x];
  __syncthreads();
  const int t = blockIdx.x * 256 + threadIdx.x;   // b*NF + i
  const int b = t / NF;
  const int i = t % NF;
  float dg = 0.f;
#pragma unroll 8
  for (int c = 0; c < 32; ++c) dg += degP[(size_t)c * NF + i];
  float xv[16];
  const float* xp = x + (size_t)t * 16;
#pragma unroll
  for (int d = 0; d < 16; ++d) xv[d] = xp[d];
  const float di = dg > 0.f ? rsqrtf(dg) : 0.f;
  if (b == 0) dinv[i] = di;
  const int base = ((i >> 3) * 64 + b * 16) * 8 + (i & 7);
#pragma unroll
  for (int o = 0; o < 16; ++o) {
    float h = 0.f;
#pragma unroll
    for (int d = 0; d < 16; ++d) h += xv[d] * w[d * 16 + o];
    gp[base + o * 8] = (_Float16)(h * di);
  }
}

// ---------------------------------------------------------------------------
// k_gemm3: Cp[j][p][bo] = sum_{i in split p} Ah[i,j] * g[i,bo] via
// mfma_f32_16x16x32_f16.  K-chunk = 128 rows (10 barriers per block).
// LDS: [j:64][i-pair:64+4pad] u32 (half pairs, even k in lo16) ->
// halfword index within a row == k_local directly.
//   staging: b32 writes; fragment reads: 16-B aligned ds_read_b128,
//   row stride 272 B -> <=2-way bank aliasing (free).
// A-frag: lane(m=x, k=s*32+q*8+jj) = Ah[kbase+k][jbase+ms*16+x]
//   -> halfword offset (ms*16+x)*136 + s*32 + q*8.        [BUG FIX vs R3:
//   was s*64, misaligning A vs B in k for s>=1 and overrunning the row]
// C/D: col=lane&15 (bo), row=q*4+reg (j_local).
// ---------------------------------------------------------------------------
__global__ __launch_bounds__(256) void k_gemm3(const _Float16* __restrict__ Ah,
                                               const half8_t* __restrict__ gp8,
                                               float* __restrict__ Cp,
                                               int kRange, int nchunk) {
  __shared__ unsigned int lds32[64 * 68];   // 17.4 KB
  const int tid = threadIdx.x;
  const int lane = tid & 63;
  const int w = tid >> 6;        // wave id = bo-slice
  const int x = lane & 15;
  const int q = lane >> 4;
  const int jbase = blockIdx.x * 64;
  const int kbase0 = blockIdx.y * kRange;
  const int cq = tid & 15;       // staging j-quad
  const int ip = tid >> 4;       // staging i-pair 0..15

  floatx4 acc[4] = {};

  for (int ch = 0; ch < nchunk; ++ch) {
    const int kbase = kbase0 + ch * 128;
    __syncthreads();                         // protect LDS from prev readers
#pragma unroll
    for (int p = 0; p < 4; ++p) {
      const int il = p * 32 + ip * 2;
      const _Float16* r0 = Ah + (size_t)(kbase + il) * NF + jbase + cq * 4;
      const ushort4 a0 = *(const ushort4*)r0;        // row i   (even k)
      const ushort4 a1 = *(const ushort4*)(r0 + NF); // row i+1 (odd k)
      unsigned int* d = &lds32[(cq * 4) * 68 + p * 16 + ip];
      d[0]   = (unsigned)a0.x | ((unsigned)a1.x << 16);
      d[68]  = (unsigned)a0.y | ((unsigned)a1.y << 16);
      d[136] = (unsigned)a0.z | ((unsigned)a1.z << 16);
      d[204] = (unsigned)a0.w | ((unsigned)a1.w << 16);
    }
    __syncthreads();
    const int k8base = kbase >> 3;
#pragma unroll
    for (int s = 0; s < 4; ++s) {
      const half8_t bfrag = gp8[(k8base + s * 4 + q) * 64 + w * 16 + x];
#pragma unroll
      for (int ms = 0; ms < 4; ++ms) {
        const half8_t afrag = *(const half8_t*)((const _Float16*)lds32 +
                                (ms * 16 + x) * 136 + s * 32 + q * 8);
        acc[ms] = __builtin_amdgcn_mfma_f32_16x16x32_f16(afrag, bfrag,
                                                         acc[ms], 0, 0, 0);
      }
    }
  }

  const int p = blockIdx.y;
#pragma unroll
  for (int ms = 0; ms < 4; ++ms) {
#pragma unroll
    for (int r = 0; r < 4; ++r) {
      const int j = jbase + ms * 16 + q * 4 + r;
      Cp[((size_t)j * 8 + p) * 64 + w * 16 + x] = acc[ms][r];
    }
  }
}

// ---------------------------------------------------------------------------
// k_out: per n: the 20-KB Cp slab for j=n*10..n*10+9 is contiguous ->
// coalesced float4 stage to LDS; reduce over p; relu(dinv*C + b_gcn);
// (160) @ W_out(160,16) + b_out.
// ---------------------------------------------------------------------------
__global__ __launch_bounds__(256) void k_out(const float* __restrict__ Cp,
                                             const float* __restrict__ dinv,
                                             const float* __restrict__ bgcn,
                                             const float* __restrict__ Wout,
                                             const float* __restrict__ bout,
                                             float* __restrict__ out) {
  __shared__ float wl[2560];
  __shared__ float cps[5120];   // [f:10][p:8][bo:64]
  __shared__ float tmp[640];
  const int n = blockIdx.x;
  const int t = threadIdx.x;
  {
    const float4* src = (const float4*)(Cp + (size_t)n * 5120);
    float4* dst = (float4*)cps;
#pragma unroll
    for (int r = 0; r < 5; ++r) dst[t + r * 256] = src[t + r * 256];
    const float4* ws = (const float4*)Wout;
    float4* wd = (float4*)wl;
#pragma unroll
    for (int r = 0; r < 2; ++r) wd[t + r * 256] = ws[t + r * 256];
    if (t < 128) wd[512 + t] = ws[512 + t];
  }
  __syncthreads();
  if (t < 160) {
    const int f = t >> 4, o = t & 15;
    const float di = dinv[n * 10 + f];
    const float bg = bgcn[o];
#pragma unroll
    for (int b = 0; b < 4; ++b) {
      float s = 0.f;
#pragma unroll
      for (int p = 0; p < 8; ++p) s += cps[(f * 8 + p) * 64 + b * 16 + o];
      const float v = di * s + bg;
      tmp[b * 160 + t] = v > 0.f ? v : 0.f;
    }
  }
  __syncthreads();
  if (t < 64) {
    const int b = t >> 4, oc = t & 15;
    float acc = bout[oc];
    for (int k = 0; k < 160; ++k) acc += tmp[b * 160 + k] * wl[k * 16 + oc];
    out[((size_t)(b * 1024 + n)) * 16 + oc] = acc;
  }
}

// ---------------------------------------------------------------------------
extern "C" void kernel_launch(void* const* d_in, const int* in_sizes, int n_in,
                              void* d_out, int out_size, void* d_ws,
                              size_t ws_size, hipStream_t stream) {
  const float* x   = (const float*)d_in[0];   // (4,1024,10,16)
  const float* sup = (const float*)d_in[3];   // (10240,10240)
  const float* Wg  = (const float*)d_in[6];   // (16,16)
  const float* bg  = (const float*)d_in[7];   // (16,)
  const float* Wo  = (const float*)d_in[8];   // (160,16)
  const float* bo  = (const float*)d_in[9];   // (16,)
  float* out = (float*)d_out;

  char* ws = (char*)d_ws;
  float*     degP = (float*)ws;                           // 32*NF*4 = 1.31 MB
  float*     dinv = (float*)(ws + 1310720);               // 40 KB
  _Float16*  gp   = (_Float16*)(ws + 1351680);            // 1.31 MB
  _Float16*  Ah   = (_Float16*)(ws + 2662400);            // 210 MB fp16 A'
  float*     Cp   = (float*)(ws + 2662400 + 209715200);   // 21 MB partials

  const int S = 8;                  // K-split factor
  const int kRange = NF / S;        // 1280
  const int nchunk = kRange / 128;  // 10

  k_prep<<<dim3(40, 32), 256, 0, stream>>>(sup, Ah, degP);
  k_g<<<160, 256, 0, stream>>>(x, Wg, degP, dinv, gp);
  k_gemm3<<<dim3(160, S), 256, 0, stream>>>(Ah, (const half8_t*)gp, Cp,
                                            kRange, nchunk);
  k_out<<<1024, 256, 0, stream>>>(Cp, dinv, bg, Wo, bo, out);
}